// Round 1
// baseline (2362.532 us; speedup 1.0000x reference)
//
#include <hip/hip_runtime.h>

#define NB 32
#define NLEN 128
#define NS 96
#define NE 768
#define NH 300
#define NR 41

// workspace offsets (in floats)
#define OFF_TSUM   0u
#define OFF_ELEN   24576u
#define OFF_RLEN   24608u
#define OFF_HCM    24640u
#define OFF_TAB    34240u
#define OFF_HGA    49240u
#define OFF_HGB    970840u
#define OFF_SWT    1892440u
#define OFF_U      1904740u
#define OFF_SPRE   2030692u
#define OFF_RDEN   2156644u
#define OFF_C      2282596u
#define OFF_M      2408548u

__device__ __forceinline__ float wave_reduce(float v) {
#pragma unroll
  for (int off = 32; off > 0; off >>= 1) v += __shfl_down(v, off);
  return v;
}

// ---- tsum[b,e] = sum_l text[b,l,e] ----
__global__ void k_tsum(const float* __restrict__ text, float* __restrict__ tsum) {
  int b = blockIdx.x;
  int tid = threadIdx.x;
  for (int e = tid; e < NE; e += 256) {
    const float* p = text + (size_t)b * NLEN * NE + e;
    float s = 0.f;
#pragma unroll 4
    for (int l = 0; l < NLEN; ++l) s += p[(size_t)l * NE];
    tsum[b * NE + e] = s;
  }
}

// ---- lengths ----
__global__ void k_len(const int* __restrict__ cm, const int* __restrict__ pt,
                      float* __restrict__ elen, float* __restrict__ rlen) {
  int b = threadIdx.x;
  if (b < NB) {
    int s1 = 0;
    for (int l = 0; l < NLEN; ++l) s1 += cm[b * NLEN + l];
    int s2 = 0;
    for (int s = 0; s < NS; ++s) s2 += (pt[b * NS + s] != 0) ? 1 : 0;
    elen[b] = (float)s1;
    rlen[b] = (float)s2;
  }
}

// ---- hc_mean[b,h] = (tsum[b]·linW[:,h] + L*linb[h]) / elen[b] ----
__global__ void k_hcmean(const float* __restrict__ tsum, const float* __restrict__ linW,
                         const float* __restrict__ linb, const float* __restrict__ elen,
                         float* __restrict__ hcm) {
  int idx = blockIdx.x * 256 + threadIdx.x;
  if (idx >= NB * NH) return;
  int b = idx / NH, h = idx - b * NH;
  const float* tp = tsum + b * NE;
  float s = 0.f;
  for (int e = 0; e < NE; ++e) s += tp[e] * linW[(size_t)e * NH + h];
  hcm[idx] = (s + (float)NLEN * linb[h]) / elen[b];
}

// ---- table[p,h] = pos_emb[p]·linW[:,h] + linb[h] ----
__global__ void k_table(const float* __restrict__ pemb, const float* __restrict__ linW,
                        const float* __restrict__ linb, float* __restrict__ tab) {
  int idx = blockIdx.x * 256 + threadIdx.x;
  if (idx >= 50 * NH) return;
  int p = idx / NH, h = idx - p * NH;
  const float* pp = pemb + (size_t)p * NE;
  float s = 0.f;
  for (int e = 0; e < NE; ++e) s += pp[e] * linW[(size_t)e * NH + h];
  tab[idx] = s + linb[h];
}

// ---- hg0[b,s,h] = table[pt[b,s],h] ----
__global__ void k_gather(const int* __restrict__ pt, const float* __restrict__ tab,
                         float* __restrict__ hg) {
  int idx = blockIdx.x * 256 + threadIdx.x;
  if (idx >= NB * NS * NH) return;
  int h = idx % NH;
  int bs = idx / NH;
  hg[idx] = tab[pt[bs] * NH + h];
}

// ---- swt[r,i] = sum_o W[r,i,o]*sw[o] (wave per row) ----
__global__ void k_swt(const float* __restrict__ Wl, const float* __restrict__ sw,
                      float* __restrict__ swt) {
  int gw = (blockIdx.x * blockDim.x + threadIdx.x) >> 6;
  int lane = threadIdx.x & 63;
  if (gw >= NR * NH) return;
  const float* wp = Wl + (size_t)gw * NH;
  float s = 0.f;
  for (int o = lane; o < NH; o += 64) s += wp[o] * sw[o];
  s = wave_reduce(s);
  if (lane == 0) swt[gw] = s;
}

// ---- u[b,r,t] = x[b,t,:]·swt[r,:] (wave per row) ----
__global__ void k_u(const float* __restrict__ x, const float* __restrict__ swt,
                    float* __restrict__ u) {
  int gw = (blockIdx.x * blockDim.x + threadIdx.x) >> 6;
  int lane = threadIdx.x & 63;
  if (gw >= NB * NR * NS) return;
  int t = gw % NS;
  int br = gw / NS;
  int r = br % NR;
  int b = br / NR;
  const float* xp = x + (size_t)(b * NS + t) * NH;
  const float* sp = swt + (size_t)r * NH;
  float s = 0.f;
  for (int i = lane; i < NH; i += 64) s += xp[i] * sp[i];
  s = wave_reduce(s);
  if (lane == 0) u[gw] = s;
}

// ---- denom + v + pre-softmax scores (wave per (b,r,s)) ----
__global__ void k_scores(const float* __restrict__ adj, const float* __restrict__ u,
                         const float* __restrict__ sb, float* __restrict__ spre,
                         float* __restrict__ rden) {
  int gw = (blockIdx.x * blockDim.x + threadIdx.x) >> 6;
  int lane = threadIdx.x & 63;
  if (gw >= NB * NR * NS) return;
  int s = gw % NS;
  int br = gw / NS;
  int r = br % NR;
  int b = br / NR;
  const float* ap = adj + (size_t)gw * NS;   // adj[b][r][s][:]
  const float* up = u + (size_t)br * NS;
  float d = 0.f, v = 0.f;
  for (int t = lane; t < NS; t += 64) {
    float a = ap[t];
    d += a;
    v += a * up[t];
  }
  d = wave_reduce(d);
  v = wave_reduce(v);
  if (lane == 0) {
    float ds = (d == 0.f) ? 1.f : d;
    int o = (b * NS + s) * NR + r;
    spre[o] = v / ds + sb[0];
    rden[o] = 1.f / ds;
  }
}

// ---- softmax over r + fold 1/denom: c[b,r,s] ----
__global__ void k_softmax(const float* __restrict__ spre, const float* __restrict__ rden,
                          float* __restrict__ c) {
  int bs = blockIdx.x * 256 + threadIdx.x;
  if (bs >= NB * NS) return;
  int b = bs / NS, s = bs - b * NS;
  float vals[NR];
  float m = -1e30f;
#pragma unroll
  for (int r = 0; r < NR; ++r) {
    vals[r] = spre[(size_t)bs * NR + r];
    m = fmaxf(m, vals[r]);
  }
  float sum = 0.f;
#pragma unroll
  for (int r = 0; r < NR; ++r) {
    float e = expf(vals[r] - m);
    vals[r] = e;
    sum += e;
  }
  float inv = 1.f / sum;
#pragma unroll
  for (int r = 0; r < NR; ++r) {
    c[((size_t)(b * NR + r)) * NS + s] = vals[r] * inv * rden[(size_t)bs * NR + r];
  }
}

// ---- M[b,s,(rg,i)] = c[b,r,s] * (adj[b,r] @ x[b])[s,i]  (block per (b,rg,i-chunk)) ----
__global__ __launch_bounds__(384)
void k_pmat(const float* __restrict__ adj, const float* __restrict__ x,
            const float* __restrict__ c, float* __restrict__ M,
            int r0, int rgn) {
  __shared__ float At[96 * 100];  // adj transposed: At[t][s]
  __shared__ float Xl[96 * 68];   // x chunk: Xl[t][ii]
  const int tid = threadIdx.x;
  int bid = blockIdx.x;
  const int ic = bid % 5; bid /= 5;
  const int rg = bid % rgn;
  const int b = bid / rgn;
  const int r = r0 + rg;
  const int i0 = ic << 6;
  const int iw = (i0 + 64 <= NH) ? 64 : (NH - i0);

  const float* ap = adj + (size_t)(b * NR + r) * NS * NS;
  for (int idx = tid; idx < NS * NS; idx += 384) {
    int s = idx / 96, t = idx - s * 96;
    At[t * 100 + s] = ap[idx];
  }
  const float* xp = x + (size_t)b * NS * NH;
  for (int idx = tid; idx < 96 * 64; idx += 384) {
    int t = idx >> 6, ii = idx & 63;
    Xl[t * 68 + ii] = (ii < iw) ? xp[(size_t)t * NH + i0 + ii] : 0.f;
  }
  __syncthreads();

  const int sg = tid % 24;
  const int ig = tid / 24;      // 0..15
  const int s0 = sg << 2;
  const int ii0 = ig << 2;
  float acc[4][4] = {};
#pragma unroll 4
  for (int t = 0; t < 96; ++t) {
    float4 av = *(const float4*)&At[t * 100 + s0];
    float4 xv = *(const float4*)&Xl[t * 68 + ii0];
    float as[4] = {av.x, av.y, av.z, av.w};
    float xs[4] = {xv.x, xv.y, xv.z, xv.w};
#pragma unroll
    for (int i = 0; i < 4; ++i)
#pragma unroll
      for (int j = 0; j < 4; ++j)
        acc[i][j] += as[i] * xs[j];
  }

  if (ii0 < iw) {
    const size_t Kst = (size_t)rgn * NH;
#pragma unroll
    for (int i = 0; i < 4; ++i) {
      int s = s0 + i;
      float cc = c[(size_t)(b * NR + r) * NS + s];
      float* mp = M + ((size_t)(b * NS) + s) * Kst + (size_t)rg * NH + i0 + ii0;
      mp[0] = acc[i][0] * cc;
      mp[1] = acc[i][1] * cc;
      mp[2] = acc[i][2] * cc;
      mp[3] = acc[i][3] * cc;
    }
  }
}

// ---- y[3072,300] (+)= M[3072,K] @ Bw[K,300]; relu on last group ----
__global__ __launch_bounds__(256)
void k_gemm(const float* __restrict__ A, const float* __restrict__ Bw,
            float* __restrict__ y, int K, int first, int last) {
  __shared__ float Al[2][32 * 68];  // Al[k][row]
  __shared__ float Bl[2][32 * 68];  // Bl[k][col]
  const int tid = threadIdx.x;
  const int row0 = blockIdx.x << 6;
  const int o0 = blockIdx.y << 6;
  const int rg = tid & 15;
  const int og = tid >> 4;
  float acc[4][4] = {};
  float ra[8], rb[8];
  const int nt = (K + 31) >> 5;

#pragma unroll
  for (int j = 0; j < 8; ++j) {
    int idx = tid + (j << 8);
    int ridx = idx >> 5, kk = idx & 31;
    ra[j] = (kk < K) ? A[(size_t)(row0 + ridx) * K + kk] : 0.f;
    int kb = idx >> 6, oo = idx & 63;
    int oc = o0 + oo;
    rb[j] = (kb < K && oc < NH) ? Bw[(size_t)kb * NH + oc] : 0.f;
  }
#pragma unroll
  for (int j = 0; j < 8; ++j) {
    int idx = tid + (j << 8);
    Al[0][(idx & 31) * 68 + (idx >> 5)] = ra[j];
    Bl[0][(idx >> 6) * 68 + (idx & 63)] = rb[j];
  }
  __syncthreads();

  for (int tI = 0; tI < nt; ++tI) {
    int cur = tI & 1;
    if (tI + 1 < nt) {
      int kt = (tI + 1) << 5;
#pragma unroll
      for (int j = 0; j < 8; ++j) {
        int idx = tid + (j << 8);
        int ridx = idx >> 5, kk = kt + (idx & 31);
        ra[j] = (kk < K) ? A[(size_t)(row0 + ridx) * K + kk] : 0.f;
        int kb = kt + (idx >> 6), oo = idx & 63;
        int oc = o0 + oo;
        rb[j] = (kb < K && oc < NH) ? Bw[(size_t)kb * NH + oc] : 0.f;
      }
    }
    const float* Ac = Al[cur];
    const float* Bc = Bl[cur];
#pragma unroll
    for (int kk = 0; kk < 32; ++kk) {
      float4 av = *(const float4*)&Ac[kk * 68 + (rg << 2)];
      float4 bv = *(const float4*)&Bc[kk * 68 + (og << 2)];
      float as[4] = {av.x, av.y, av.z, av.w};
      float bs[4] = {bv.x, bv.y, bv.z, bv.w};
#pragma unroll
      for (int i = 0; i < 4; ++i)
#pragma unroll
        for (int j = 0; j < 4; ++j)
          acc[i][j] += as[i] * bs[j];
    }
    __syncthreads();
    if (tI + 1 < nt) {
      int nxt = cur ^ 1;
#pragma unroll
      for (int j = 0; j < 8; ++j) {
        int idx = tid + (j << 8);
        Al[nxt][(idx & 31) * 68 + (idx >> 5)] = ra[j];
        Bl[nxt][(idx >> 6) * 68 + (idx & 63)] = rb[j];
      }
      __syncthreads();
    }
  }

#pragma unroll
  for (int i = 0; i < 4; ++i) {
    int row = row0 + (rg << 2) + i;
#pragma unroll
    for (int j = 0; j < 4; ++j) {
      int col = o0 + (og << 2) + j;
      if (col < NH) {
        size_t off = (size_t)row * NH + col;
        float v = acc[i][j];
        if (!first) v += y[off];
        if (last) v = fmaxf(v, 0.f);
        y[off] = v;
      }
    }
  }
}

// ---- final: out[b,:] = concat(hg_mean, hc_mean) @ dW + db ----
__global__ void k_final(const float* __restrict__ hg, const float* __restrict__ rlen,
                        const float* __restrict__ hcm, const float* __restrict__ dW,
                        const float* __restrict__ db, float* __restrict__ out) {
  int b = blockIdx.x;
  __shared__ float hgm[NH];
  int tid = threadIdx.x;
  for (int h = tid; h < NH; h += 256) {
    float s = 0.f;
    for (int ss = 0; ss < NS; ++ss) s += hg[((size_t)(b * NS) + ss) * NH + h];
    hgm[h] = s / rlen[b];
  }
  __syncthreads();
  if (tid < 3) {
    float s = db[tid];
    for (int h = 0; h < NH; ++h) s += hgm[h] * dW[h * 3 + tid];
    for (int h = 0; h < NH; ++h) s += hcm[b * NH + h] * dW[(NH + h) * 3 + tid];
    out[b * 3 + tid] = s;
  }
}

extern "C" void kernel_launch(void* const* d_in, const int* in_sizes, int n_in,
                              void* d_out, int out_size, void* d_ws, size_t ws_size,
                              hipStream_t stream) {
  (void)in_sizes; (void)n_in; (void)out_size;
  const float* text   = (const float*)d_in[0];
  const int*   cmask  = (const int*)d_in[1];
  const int*   ptags  = (const int*)d_in[2];
  const float* adj    = (const float*)d_in[3];
  const float* pemb   = (const float*)d_in[4];
  const float* linW   = (const float*)d_in[5];
  const float* linb   = (const float*)d_in[6];
  const float* rgcnW  = (const float*)d_in[7];
  const float* scoreW = (const float*)d_in[8];
  const float* scoreB = (const float*)d_in[9];
  const float* denseW = (const float*)d_in[10];
  const float* denseB = (const float*)d_in[11];
  float* out = (float*)d_out;
  float* ws = (float*)d_ws;

  float* tsum = ws + OFF_TSUM;
  float* elen = ws + OFF_ELEN;
  float* rlen = ws + OFF_RLEN;
  float* hcm  = ws + OFF_HCM;
  float* tab  = ws + OFF_TAB;
  float* hgA  = ws + OFF_HGA;
  float* hgB  = ws + OFF_HGB;
  float* swt  = ws + OFF_SWT;
  float* ubuf = ws + OFF_U;
  float* spre = ws + OFF_SPRE;
  float* rden = ws + OFF_RDEN;
  float* cbuf = ws + OFF_C;
  float* Mbuf = ws + OFF_M;

  size_t avail = ws_size / sizeof(float);
  size_t mcap = (avail > OFF_M) ? (avail - OFF_M) : 0;
  int RG = (int)(mcap / ((size_t)NB * NS * NH));
  if (RG > NR) RG = NR;
  if (RG < 1) RG = 1;

  k_tsum<<<dim3(NB), dim3(256), 0, stream>>>(text, tsum);
  k_len<<<dim3(1), dim3(64), 0, stream>>>(cmask, ptags, elen, rlen);
  k_hcmean<<<dim3((NB * NH + 255) / 256), dim3(256), 0, stream>>>(tsum, linW, linb, elen, hcm);
  k_table<<<dim3((50 * NH + 255) / 256), dim3(256), 0, stream>>>(pemb, linW, linb, tab);
  k_gather<<<dim3((NB * NS * NH + 255) / 256), dim3(256), 0, stream>>>(ptags, tab, hgA);

  float* x = hgA;
  float* yb = hgB;
  for (int l = 0; l < 2; ++l) {
    const float* Wl = rgcnW + (size_t)l * NR * NH * NH;
    k_swt<<<dim3((NR * NH) / 4), dim3(256), 0, stream>>>(Wl, scoreW + l * NH, swt);
    k_u<<<dim3((NB * NR * NS) / 4), dim3(256), 0, stream>>>(x, swt, ubuf);
    k_scores<<<dim3((NB * NR * NS) / 4), dim3(256), 0, stream>>>(adj, ubuf, scoreB + l, spre, rden);
    k_softmax<<<dim3((NB * NS + 255) / 256), dim3(256), 0, stream>>>(spre, rden, cbuf);
    int ng = (NR + RG - 1) / RG;
    for (int g = 0; g < ng; ++g) {
      int r0 = g * RG;
      int rgn = (r0 + RG <= NR) ? RG : (NR - r0);
      k_pmat<<<dim3(NB * rgn * 5), dim3(384), 0, stream>>>(adj, x, cbuf, Mbuf, r0, rgn);
      k_gemm<<<dim3(48, 5), dim3(256), 0, stream>>>(Mbuf, Wl + (size_t)r0 * NH * NH, yb,
                                                    rgn * NH, (g == 0) ? 1 : 0,
                                                    (g == ng - 1) ? 1 : 0);
    }
    float* tswap = x; x = yb; yb = tswap;
  }
  k_final<<<dim3(NB), dim3(256), 0, stream>>>(x, rlen, hcm, denseW, denseB, out);
}

// Round 3
// 2087.026 us; speedup vs baseline: 1.1320x; 1.1320x over previous
//
#include <hip/hip_runtime.h>

#define NB 32
#define NLEN 128
#define NS 96
#define NE 768
#define NH 300
#define NR 41
#define RCH 7     // r-chunks (6,6,6,6,6,6,5)
#define RPC 6
#define OCT 5     // o-tiles of 64

// workspace offsets (in floats)
#define OFF_TSUM   0u
#define OFF_ELEN   24576u
#define OFF_RLEN   24608u
#define OFF_HCM    24640u
#define OFF_TAB    34240u
#define OFF_HGA    49240u
#define OFF_HGB    970840u
#define OFF_SWT    1892440u
#define OFF_U      1904740u
#define OFF_SPRE   2030692u
#define OFF_RDEN   2156644u
#define OFF_C      2282596u
#define OFF_P      2408548u   // [RCH][NB][NS][NH] f32 = 6451200 floats

// swizzle: spread 32-float groups by 4 to kill quad-bank collisions; keeps
// 4-aligned quads and 8-runs contiguous (quads never cross a 32 boundary).
__device__ __forceinline__ int SW(int o) { return o + ((o >> 5) << 2); }

__device__ __forceinline__ float wave_reduce(float v) {
#pragma unroll
  for (int off = 32; off > 0; off >>= 1) v += __shfl_down(v, off);
  return v;
}

// ---- tsum[b,e] = sum_l text[b,l,e] ----
__global__ void k_tsum(const float* __restrict__ text, float* __restrict__ tsum) {
  int b = blockIdx.x;
  int tid = threadIdx.x;
  for (int e = tid; e < NE; e += 256) {
    const float* p = text + (size_t)b * NLEN * NE + e;
    float s = 0.f;
#pragma unroll 4
    for (int l = 0; l < NLEN; ++l) s += p[(size_t)l * NE];
    tsum[b * NE + e] = s;
  }
}

// ---- lengths ----
__global__ void k_len(const int* __restrict__ cm, const int* __restrict__ pt,
                      float* __restrict__ elen, float* __restrict__ rlen) {
  int b = threadIdx.x;
  if (b < NB) {
    int s1 = 0;
    for (int l = 0; l < NLEN; ++l) s1 += cm[b * NLEN + l];
    int s2 = 0;
    for (int s = 0; s < NS; ++s) s2 += (pt[b * NS + s] != 0) ? 1 : 0;
    elen[b] = (float)s1;
    rlen[b] = (float)s2;
  }
}

// ---- hc_mean[b,h] = (tsum[b]·linW[:,h] + L*linb[h]) / elen[b] ----
__global__ void k_hcmean(const float* __restrict__ tsum, const float* __restrict__ linW,
                         const float* __restrict__ linb, const float* __restrict__ elen,
                         float* __restrict__ hcm) {
  int idx = blockIdx.x * 256 + threadIdx.x;
  if (idx >= NB * NH) return;
  int b = idx / NH, h = idx - b * NH;
  const float* tp = tsum + b * NE;
  float s = 0.f;
  for (int e = 0; e < NE; ++e) s += tp[e] * linW[(size_t)e * NH + h];
  hcm[idx] = (s + (float)NLEN * linb[h]) / elen[b];
}

// ---- table[p,h] = pos_emb[p]·linW[:,h] + linb[h] ----
__global__ void k_table(const float* __restrict__ pemb, const float* __restrict__ linW,
                        const float* __restrict__ linb, float* __restrict__ tab) {
  int idx = blockIdx.x * 256 + threadIdx.x;
  if (idx >= 50 * NH) return;
  int p = idx / NH, h = idx - p * NH;
  const float* pp = pemb + (size_t)p * NE;
  float s = 0.f;
  for (int e = 0; e < NE; ++e) s += pp[e] * linW[(size_t)e * NH + h];
  tab[idx] = s + linb[h];
}

// ---- hg0[b,s,h] = table[pt[b,s],h] ----
__global__ void k_gather(const int* __restrict__ pt, const float* __restrict__ tab,
                         float* __restrict__ hg) {
  int idx = blockIdx.x * 256 + threadIdx.x;
  if (idx >= NB * NS * NH) return;
  int h = idx % NH;
  int bs = idx / NH;
  hg[idx] = tab[pt[bs] * NH + h];
}

// ---- swt[r,i] = sum_o W[r,i,o]*sw[o] ----
__global__ void k_swt(const float* __restrict__ Wl, const float* __restrict__ sw,
                      float* __restrict__ swt) {
  int gw = (blockIdx.x * blockDim.x + threadIdx.x) >> 6;
  int lane = threadIdx.x & 63;
  if (gw >= NR * NH) return;
  const float* wp = Wl + (size_t)gw * NH;
  float s = 0.f;
  for (int o = lane; o < NH; o += 64) s += wp[o] * sw[o];
  s = wave_reduce(s);
  if (lane == 0) swt[gw] = s;
}

// ---- u[b,r,t] = x[b,t,:]·swt[r,:] ----
__global__ void k_u(const float* __restrict__ x, const float* __restrict__ swt,
                    float* __restrict__ u) {
  int gw = (blockIdx.x * blockDim.x + threadIdx.x) >> 6;
  int lane = threadIdx.x & 63;
  if (gw >= NB * NR * NS) return;
  int t = gw % NS;
  int br = gw / NS;
  int r = br % NR;
  int b = br / NR;
  const float* xp = x + (size_t)(b * NS + t) * NH;
  const float* sp = swt + (size_t)r * NH;
  float s = 0.f;
  for (int i = lane; i < NH; i += 64) s += xp[i] * sp[i];
  s = wave_reduce(s);
  if (lane == 0) u[gw] = s;
}

// ---- denom + v + pre-softmax scores ----
__global__ void k_scores(const float* __restrict__ adj, const float* __restrict__ u,
                         const float* __restrict__ sb, float* __restrict__ spre,
                         float* __restrict__ rden) {
  int gw = (blockIdx.x * blockDim.x + threadIdx.x) >> 6;
  int lane = threadIdx.x & 63;
  if (gw >= NB * NR * NS) return;
  int s = gw % NS;
  int br = gw / NS;
  int r = br % NR;
  int b = br / NR;
  const float* ap = adj + (size_t)gw * NS;
  const float* up = u + (size_t)br * NS;
  float d = 0.f, v = 0.f;
  for (int t = lane; t < NS; t += 64) {
    float a = ap[t];
    d += a;
    v += a * up[t];
  }
  d = wave_reduce(d);
  v = wave_reduce(v);
  if (lane == 0) {
    float ds = (d == 0.f) ? 1.f : d;
    int o = (b * NS + s) * NR + r;
    spre[o] = v / ds + sb[0];
    rden[o] = 1.f / ds;
  }
}

// ---- softmax over r, fold 1/denom: c[b,r,s] ----
__global__ void k_softmax(const float* __restrict__ spre, const float* __restrict__ rden,
                          float* __restrict__ c) {
  int bs = blockIdx.x * 256 + threadIdx.x;
  if (bs >= NB * NS) return;
  int b = bs / NS, s = bs - b * NS;
  float vals[NR];
  float m = -1e30f;
#pragma unroll
  for (int r = 0; r < NR; ++r) {
    vals[r] = spre[(size_t)bs * NR + r];
    m = fmaxf(m, vals[r]);
  }
  float sum = 0.f;
#pragma unroll
  for (int r = 0; r < NR; ++r) {
    float e = expf(vals[r] - m);
    vals[r] = e;
    sum += e;
  }
  float inv = 1.f / sum;
#pragma unroll
  for (int r = 0; r < NR; ++r) {
    c[((size_t)(b * NR + r)) * NS + s] = vals[r] * inv * rden[(size_t)bs * NR + r];
  }
}

// ---- fused per-relation: Ht = x[b]@W_r[:,o-tile]; accO += (c⊙adjT)@Ht ----
// block = (b, rg, oc); 192 threads; micro-tile 4(rows)x8(cols)
__global__ __launch_bounds__(192)
void k_fused(const float* __restrict__ adj, const float* __restrict__ x,
             const float* __restrict__ cbuf, const float* __restrict__ Wl,
             float* __restrict__ P) {
  __shared__ __align__(16) float sA[32 * 108];  // x-chunk / adj-chunk, k-major, swz cols
  __shared__ __align__(16) float sB[32 * 68];   // W-chunk, k-major, swz cols
  __shared__ __align__(16) float sH[96 * 68];   // Ht, t-major rows, swz o-cols

  const int tid = threadIdx.x;
  int bid = blockIdx.x;
  const int oc = bid % OCT; bid /= OCT;
  const int rg = bid % RCH;
  const int b = bid / RCH;
  const int o0 = oc * 64;
  const int r0 = rg * RPC;
  const int nr = (r0 + RPC <= NR) ? RPC : (NR - r0);

  const int g1 = tid >> 3;        // 0..23 row-group (t in gemm1, s in gemm2)
  const int g2 = tid & 7;         // 0..7  col-group
  const int fa = SW(g1 * 4);
  const int fb = SW(g2 * 8);      // 8-run stays contiguous under SW

  float accO[4][8];
#pragma unroll
  for (int i = 0; i < 4; ++i)
#pragma unroll
    for (int j = 0; j < 8; ++j) accO[i][j] = 0.f;

  const float* xb = x + (size_t)b * NS * NH;

  for (int rr = 0; rr < nr; ++rr) {
    const int r = r0 + rr;
    const float* wp = Wl + (size_t)r * NH * NH;
    const float* ap = adj + (size_t)(b * NR + r) * NS * NS;
    const float* cp = cbuf + (size_t)(b * NR + r) * NS;

    float acc1[4][8];
#pragma unroll
    for (int i = 0; i < 4; ++i)
#pragma unroll
      for (int j = 0; j < 8; ++j) acc1[i][j] = 0.f;

    // ---- GEMM1: Ht[t][o] = sum_k x[b][t][k] * W[r][k][o0+o], K=300 in 10 chunks
    for (int kc = 0; kc < 10; ++kc) {
      const int k0 = kc * 32;
      __syncthreads();  // prev compute done before restage
      // stage x: kq minor for coalescing, transposed write [kk][SW(t)]
#pragma unroll
      for (int p = 0; p < 4; ++p) {
        int idx = tid + p * 192;
        int kq = (idx & 7) * 4;
        int t = idx >> 3;
        int k = k0 + kq;
        float4 v = make_float4(0.f, 0.f, 0.f, 0.f);
        if (k + 3 < NH) v = *(const float4*)&xb[t * NH + k];  // k mult of 4, NH mult of 4
        int col = SW(t);
        sA[(kq + 0) * 108 + col] = v.x;
        sA[(kq + 1) * 108 + col] = v.y;
        sA[(kq + 2) * 108 + col] = v.z;
        sA[(kq + 3) * 108 + col] = v.w;
      }
      // stage W: [kk][SW(o)] direct float4
#pragma unroll
      for (int p = 0; p < 3; ++p) {
        int idx = tid + p * 192;
        if (idx < 512) {
          int oq = (idx & 15) * 4;
          int kk = idx >> 4;
          int k = k0 + kk;
          int o = o0 + oq;
          float4 v = make_float4(0.f, 0.f, 0.f, 0.f);
          if (k < NH) {
            const float* wrow = wp + (size_t)k * NH;
            v.x = (o + 0 < NH) ? wrow[o + 0] : 0.f;
            v.y = (o + 1 < NH) ? wrow[o + 1] : 0.f;
            v.z = (o + 2 < NH) ? wrow[o + 2] : 0.f;
            v.w = (o + 3 < NH) ? wrow[o + 3] : 0.f;
          }
          *(float4*)&sB[kk * 68 + SW(oq)] = v;
        }
      }
      __syncthreads();
#pragma unroll
      for (int kk = 0; kk < 32; ++kk) {
        float4 a = *(const float4*)&sA[kk * 108 + fa];
        float4 b0 = *(const float4*)&sB[kk * 68 + fb];
        float4 b1 = *(const float4*)&sB[kk * 68 + fb + 4];
        float as[4] = {a.x, a.y, a.z, a.w};
        float bs[8] = {b0.x, b0.y, b0.z, b0.w, b1.x, b1.y, b1.z, b1.w};
#pragma unroll
        for (int i = 0; i < 4; ++i)
#pragma unroll
          for (int j = 0; j < 8; ++j) acc1[i][j] += as[i] * bs[j];
      }
    }

    // write Ht to LDS (own cells; visibility guaranteed by next barrier)
#pragma unroll
    for (int i = 0; i < 4; ++i) {
      float4 h0 = make_float4(acc1[i][0], acc1[i][1], acc1[i][2], acc1[i][3]);
      float4 h1 = make_float4(acc1[i][4], acc1[i][5], acc1[i][6], acc1[i][7]);
      *(float4*)&sH[(g1 * 4 + i) * 68 + fb] = h0;
      *(float4*)&sH[(g1 * 4 + i) * 68 + fb + 4] = h1;
    }

    // ---- GEMM2: accO[s][o] += sum_t c[b,r,s]*adj[b,r,s,t] * Ht[t][o], K=96 in 3 chunks
    for (int tc = 0; tc < 3; ++tc) {
      const int t0 = tc * 32;
      __syncthreads();  // also publishes sH on tc==0
#pragma unroll
      for (int p = 0; p < 4; ++p) {
        int idx = tid + p * 192;
        int tq = (idx & 7) * 4;
        int s = idx >> 3;
        float4 v = *(const float4*)&ap[s * NS + t0 + tq];
        float cs = cp[s];
        int col = SW(s);
        sA[(tq + 0) * 108 + col] = v.x * cs;
        sA[(tq + 1) * 108 + col] = v.y * cs;
        sA[(tq + 2) * 108 + col] = v.z * cs;
        sA[(tq + 3) * 108 + col] = v.w * cs;
      }
      __syncthreads();
#pragma unroll
      for (int kk = 0; kk < 32; ++kk) {
        float4 a = *(const float4*)&sA[kk * 108 + fa];
        float4 b0 = *(const float4*)&sH[(t0 + kk) * 68 + fb];
        float4 b1 = *(const float4*)&sH[(t0 + kk) * 68 + fb + 4];
        float as[4] = {a.x, a.y, a.z, a.w};
        float bs[8] = {b0.x, b0.y, b0.z, b0.w, b1.x, b1.y, b1.z, b1.w};
#pragma unroll
        for (int i = 0; i < 4; ++i)
#pragma unroll
          for (int j = 0; j < 8; ++j) accO[i][j] += as[i] * bs[j];
      }
    }
  }

  // write partial P[rg][b][s][o]
  float* pp = P + ((size_t)rg * NB + b) * NS * NH;
#pragma unroll
  for (int i = 0; i < 4; ++i) {
    int s = g1 * 4 + i;
    int o = o0 + g2 * 8;
    float* row = pp + (size_t)s * NH + o;
    if (o + 7 < NH) {
      *(float4*)&row[0] = make_float4(accO[i][0], accO[i][1], accO[i][2], accO[i][3]);
      *(float4*)&row[4] = make_float4(accO[i][4], accO[i][5], accO[i][6], accO[i][7]);
    } else {
#pragma unroll
      for (int j = 0; j < 8; ++j)
        if (o + j < NH) row[j] = accO[i][j];
    }
  }
}

// ---- reduce partials + relu ----
__global__ void k_reduce(const float* __restrict__ P, float* __restrict__ y) {
  int idx = blockIdx.x * 256 + threadIdx.x;
  if (idx >= NB * NS * NH) return;
  float s = 0.f;
#pragma unroll
  for (int ch = 0; ch < RCH; ++ch) s += P[(size_t)ch * (NB * NS * NH) + idx];
  y[idx] = fmaxf(s, 0.f);
}

// ---- final: out[b,:] = concat(hg_mean, hc_mean) @ dW + db ----
__global__ void k_final(const float* __restrict__ hg, const float* __restrict__ rlen,
                        const float* __restrict__ hcm, const float* __restrict__ dW,
                        const float* __restrict__ db, float* __restrict__ out) {
  int b = blockIdx.x;
  __shared__ float hgm[NH];
  int tid = threadIdx.x;
  for (int h = tid; h < NH; h += 256) {
    float s = 0.f;
    for (int ss = 0; ss < NS; ++ss) s += hg[((size_t)(b * NS) + ss) * NH + h];
    hgm[h] = s / rlen[b];
  }
  __syncthreads();
  if (tid < 3) {
    float s = db[tid];
    for (int h = 0; h < NH; ++h) s += hgm[h] * dW[h * 3 + tid];
    for (int h = 0; h < NH; ++h) s += hcm[b * NH + h] * dW[(NH + h) * 3 + tid];
    out[b * 3 + tid] = s;
  }
}

extern "C" void kernel_launch(void* const* d_in, const int* in_sizes, int n_in,
                              void* d_out, int out_size, void* d_ws, size_t ws_size,
                              hipStream_t stream) {
  (void)in_sizes; (void)n_in; (void)out_size; (void)ws_size;
  const float* text   = (const float*)d_in[0];
  const int*   cmask  = (const int*)d_in[1];
  const int*   ptags  = (const int*)d_in[2];
  const float* adj    = (const float*)d_in[3];
  const float* pemb   = (const float*)d_in[4];
  const float* linW   = (const float*)d_in[5];
  const float* linb   = (const float*)d_in[6];
  const float* rgcnW  = (const float*)d_in[7];
  const float* scoreW = (const float*)d_in[8];
  const float* scoreB = (const float*)d_in[9];
  const float* denseW = (const float*)d_in[10];
  const float* denseB = (const float*)d_in[11];
  float* out = (float*)d_out;
  float* ws = (float*)d_ws;

  float* tsum = ws + OFF_TSUM;
  float* elen = ws + OFF_ELEN;
  float* rlen = ws + OFF_RLEN;
  float* hcm  = ws + OFF_HCM;
  float* tab  = ws + OFF_TAB;
  float* hgA  = ws + OFF_HGA;
  float* hgB  = ws + OFF_HGB;
  float* swt  = ws + OFF_SWT;
  float* ubuf = ws + OFF_U;
  float* spre = ws + OFF_SPRE;
  float* rden = ws + OFF_RDEN;
  float* cbuf = ws + OFF_C;
  float* Pbuf = ws + OFF_P;

  k_tsum<<<dim3(NB), dim3(256), 0, stream>>>(text, tsum);
  k_len<<<dim3(1), dim3(64), 0, stream>>>(cmask, ptags, elen, rlen);
  k_hcmean<<<dim3((NB * NH + 255) / 256), dim3(256), 0, stream>>>(tsum, linW, linb, elen, hcm);
  k_table<<<dim3((50 * NH + 255) / 256), dim3(256), 0, stream>>>(pemb, linW, linb, tab);
  k_gather<<<dim3((NB * NS * NH + 255) / 256), dim3(256), 0, stream>>>(ptags, tab, hgA);

  float* x = hgA;
  float* yb = hgB;
  for (int l = 0; l < 2; ++l) {
    const float* Wl = rgcnW + (size_t)l * NR * NH * NH;
    k_swt<<<dim3((NR * NH) / 4), dim3(256), 0, stream>>>(Wl, scoreW + l * NH, swt);
    k_u<<<dim3((NB * NR * NS) / 4), dim3(256), 0, stream>>>(x, swt, ubuf);
    k_scores<<<dim3((NB * NR * NS) / 4), dim3(256), 0, stream>>>(adj, ubuf, scoreB + l, spre, rden);
    k_softmax<<<dim3((NB * NS + 255) / 256), dim3(256), 0, stream>>>(spre, rden, cbuf);
    k_fused<<<dim3(NB * RCH * OCT), dim3(192), 0, stream>>>(adj, x, cbuf, Wl, Pbuf);
    k_reduce<<<dim3((NB * NS * NH + 255) / 256), dim3(256), 0, stream>>>(Pbuf, yb);
    float* tswap = x; x = yb; yb = tswap;
  }
  k_final<<<dim3(NB), dim3(256), 0, stream>>>(x, rlen, hcm, denseW, denseB, out);
}